// Round 9
// baseline (126.433 us; speedup 1.0000x reference)
//
#include <hip/hip_runtime.h>

// ARMA posterior: per chain c in DP=32, sample s:
//   A[t]     = sigmoid(a_raw[t-1, dim_idx[d]])   (A[0]=0; same for all p in d)
//   sv[t]    = softplus(s_raw[t, dim_idx[d], p])
//   z        = (1-A)*m[t,di,p] + sv*noise
//   param[t] = z + A*param[t-1]
//   lp[t]    = -log(sv) - 0.5*log2pi - 0.5*noise^2
//
// R14: R11 structure (DMA-to-LDS noise staging, pl-overwrite, 1 vmcnt(0);
// best measured) TIME-SPLIT into 2 blocks per sample (t<512 / t>=512):
// 512-thd blocks, 64KB dynamic LDS -> 2 resident blocks/CU hide the
// phase-transition bubbles that kept the 1-block/CU version at ~26us vs
// the 16us BW bound (R12's chain-split regressed via partial 128B lines;
// time-split keeps full-line ownership: a line = all 32 chains at one t).
// Cross-block carry: block (s,1) seeds its wave-scan serial fold with
// block (s,0)'s inclusive total via a 1-deep decoupled lookback in d_ws
// (agent-scope atomics; flags zeroed per launch by hipMemsetAsync).
// Deadlock-free in any schedule: h=0 blocks never wait.
#define T_DIM 1024
#define D_DIM 4
#define P_DIM 8
#define S_DIM 256
#define DP 32
#define TDP (T_DIM * DP)      // 32768 per sample
#define HALF_T 512
#define LOG2PI_F 1.8378770664093453f

typedef float vf4 __attribute__((ext_vector_type(4)));

__device__ __forceinline__ float sigmoid_fast(float x) {
    return __builtin_amdgcn_rcpf(1.0f + __expf(-x));
}

__global__ __launch_bounds__(512) void fused_scan(
    const float* __restrict__ noise,
    const float* __restrict__ m,
    const float* __restrict__ s_raw,
    const float* __restrict__ a_raw,
    const int* __restrict__ dim_idx,
    float* __restrict__ param_out,
    float* __restrict__ lp_out,
    float* __restrict__ tot,        // d_ws: [S][32] block-0 inclusive totals
    int* __restrict__ flags)        // d_ws: [S] ready flags (zeroed per launch)
{
    const int tid  = threadIdx.x;
    const int qc   = tid & 7;          // chain quad 0..7 (4 chains each)
    const int cj   = tid >> 3;         // time chunk 0..63 (8 steps each)
    const int cjw  = cj & 7;           // chunk within wave
    const int wg   = tid >> 6;         // wave 0..7
    const int lane = tid & 63;

    const int s = blockIdx.x & 255;    // sample
    const int h = blockIdx.x >> 8;     // time half 0/1 (h=1 blocks dispatch
                                       // after all h=0; same XCD as partner)

    const int d  = qc >> 1;            // output dim 0..3
    const int p0 = (qc & 1) * 4;       // first of 4 consecutive p
    const int di = dim_idx[d];

    // dynamic LDS: per-wave noise tile, 8 waves x 8KB = 64 KB
    extern __shared__ __align__(16) float nls[];
    __shared__ float wtp[8][32];       // wave-total p (per chain)
    __shared__ float wtm8[8][8];       // wave-total M (scalar per quad)
    __shared__ float wci[8][32];       // carry-in per wave (seeded for h=1)

    const size_t sbase = (size_t)s * TDP;
    const int    tbase = h * HALF_T + cj * 8;   // first t of this chunk
    const int    off0  = tbase * DP + qc * 4;

    float* lbase = nls + wg * 2048;    // this wave's 8KB region

    // ---- Phase 0a: DMA the wave's noise tile (8 x 1KB in flight).
    // Dest = wave-uniform base + lane*16B; global src per-lane (R11-proven).
#pragma unroll
    for (int k = 0; k < 8; ++k) {
        const float* g = noise + sbase + off0 + (size_t)k * DP;
        __builtin_amdgcn_global_load_lds(
            (const __attribute__((address_space(1))) void*)g,
            (__attribute__((address_space(3))) void*)(lbase + k * 256),
            16, 0, 0);
    }
    asm volatile("s_waitcnt vmcnt(0)" ::: "memory");

    // ---- Phase 0b: local 8-step scan over 4 chains out of LDS.
    float Mk[8];
    vf4   rp = (vf4){0.f, 0.f, 0.f, 0.f};
    float rm = 1.0f;
#pragma unroll
    for (int k = 0; k < 8; ++k) {
        const int t = tbase + k;
        const int o = off0 + k * DP;
        const vf4 n  = *(const vf4*)(lbase + k * 256 + lane * 4);
        const vf4 mv = *(const vf4*)(m     + (t * D_DIM + di) * P_DIM + p0);
        const vf4 sr = *(const vf4*)(s_raw + (t * D_DIM + di) * P_DIM + p0);

        float A = 0.0f;
        if (t > 0) A = sigmoid_fast(a_raw[(t - 1) * D_DIM + di]);
        const float oma = 1.0f - A;

        // softplus + negative-log-sv per chain
        vf4 sv, nl;
        sv.x = __logf(1.0f + __expf(sr.x));  nl.x = -__logf(sv.x) - 0.5f * LOG2PI_F;
        sv.y = __logf(1.0f + __expf(sr.y));  nl.y = -__logf(sv.y) - 0.5f * LOG2PI_F;
        sv.z = __logf(1.0f + __expf(sr.z));  nl.z = -__logf(sv.z) - 0.5f * LOG2PI_F;
        sv.w = __logf(1.0f + __expf(sr.w));  nl.w = -__logf(sv.w) - 0.5f * LOG2PI_F;

        vf4 lp;
        lp.x = nl.x - 0.5f * n.x * n.x;
        lp.y = nl.y - 0.5f * n.y * n.y;
        lp.z = nl.z - 0.5f * n.z * n.z;
        lp.w = nl.w - 0.5f * n.w * n.w;
        *(vf4*)(lp_out + sbase + o) = lp;   // fire-and-forget

        vf4 z;
        z.x = oma * mv.x + sv.x * n.x;
        z.y = oma * mv.y + sv.y * n.y;
        z.z = oma * mv.z + sv.z * n.z;
        z.w = oma * mv.w + sv.w * n.w;

        rp.x = z.x + A * rp.x;
        rp.y = z.y + A * rp.y;
        rp.z = z.z + A * rp.z;
        rp.w = z.w + A * rp.w;
        rm  *= A;
        Mk[k] = rm;
        // local prefix overwrites the consumed noise slot (keeps VGPR low)
        *(vf4*)(lbase + k * 256 + lane * 4) = rp;
    }

    // ---- Phase A: inclusive shfl-scan over 8 chunks within each wave
    //      combine(older(p1,m1), newer(p2,m2)) = (p2 + m2*p1, m1*m2)
#pragma unroll
    for (int off = 1; off < 8; off <<= 1) {
        const int dd = off * 8;        // lanes per chunk step
        vf4 pp;
        pp.x = __shfl_up(rp.x, dd, 64);
        pp.y = __shfl_up(rp.y, dd, 64);
        pp.z = __shfl_up(rp.z, dd, 64);
        pp.w = __shfl_up(rp.w, dd, 64);
        const float pm = __shfl_up(rm, dd, 64);
        if (cjw >= off) {
            rp.x += rm * pp.x;
            rp.y += rm * pp.y;
            rp.z += rm * pp.z;
            rp.w += rm * pp.w;
            rm *= pm;
        }
    }

    // ---- Phase B: wave totals -> serial scan over 8 waves (32 lanes),
    // seeded with the partner block's inclusive total for h=1 (lookback).
    if (cjw == 7) {
        *(vf4*)&wtp[wg][qc * 4] = rp;
        wtm8[wg][qc] = rm;
    }
    __syncthreads();
    if (tid < 32) {                    // lanes 0..31 of wave 0; tid == chain
        float c;
        if (h == 0) {
            c = 0.0f;
        } else {
            while (__hip_atomic_load(&flags[s], __ATOMIC_ACQUIRE,
                                     __HIP_MEMORY_SCOPE_AGENT) == 0)
                __builtin_amdgcn_s_sleep(8);
            c = __hip_atomic_load(&tot[s * 32 + tid], __ATOMIC_RELAXED,
                                  __HIP_MEMORY_SCOPE_AGENT);
        }
#pragma unroll
        for (int g = 0; g < 8; ++g) {
            wci[g][tid] = c;
            c = wtp[g][tid] + wtm8[g][tid >> 2] * c;
        }
        if (h == 0) {
            // publish inclusive total (= prefix at t=511) for the partner
            __hip_atomic_store(&tot[s * 32 + tid], c, __ATOMIC_RELAXED,
                               __HIP_MEMORY_SCOPE_AGENT);
            asm volatile("s_waitcnt vmcnt(0)" ::: "memory"); // all 32 lanes' stores done
            if (tid == 0)
                __hip_atomic_store(&flags[s], 1, __ATOMIC_RELEASE,
                                   __HIP_MEMORY_SCOPE_AGENT);
        }
    }
    __syncthreads();

    // ---- Phase C: per-thread carry-in = excl-in-wave composed on wave carry
    // (wci already includes the cross-block seed for h=1)
    vf4 ep;
    ep.x = __shfl_up(rp.x, 8, 64);
    ep.y = __shfl_up(rp.y, 8, 64);
    ep.z = __shfl_up(rp.z, 8, 64);
    ep.w = __shfl_up(rp.w, 8, 64);
    float em = __shfl_up(rm, 8, 64);
    if (cjw == 0) {
        ep = (vf4){0.f, 0.f, 0.f, 0.f};
        em = 1.0f;
    }
    const vf4 ci = *(const vf4*)&wci[wg][qc * 4];
    vf4 carry;
    carry.x = ep.x + em * ci.x;
    carry.y = ep.y + em * ci.y;
    carry.z = ep.z + em * ci.z;
    carry.w = ep.w + em * ci.w;

    // ---- finalize: param[t] = pl[k] + Mk[k]*carry, pl read back from LDS
#pragma unroll
    for (int k = 0; k < 8; ++k) {
        const int o = off0 + k * DP;
        const vf4 pl = *(const vf4*)(lbase + k * 256 + lane * 4);
        vf4 pv;
        pv.x = pl.x + Mk[k] * carry.x;
        pv.y = pl.y + Mk[k] * carry.y;
        pv.z = pl.z + Mk[k] * carry.z;
        pv.w = pl.w + Mk[k] * carry.w;
        *(vf4*)(param_out + sbase + o) = pv;
    }
}

// ---------------------------------------------------------------------------
extern "C" void kernel_launch(void* const* d_in, const int* in_sizes, int n_in,
                              void* d_out, int out_size, void* d_ws, size_t ws_size,
                              hipStream_t stream)
{
    // 0:y 1:age 2:m(T,D,P) 3:s_raw(T,D,P) 4:a_raw(T-1,D,1) 5:noise(S,T,D,P)
    // 6:cond_sample 7:dim_idx(D) 8:compute_log_prob
    const float* m      = (const float*)d_in[2];
    const float* s_raw  = (const float*)d_in[3];
    const float* a_raw  = (const float*)d_in[4];
    const float* noise  = (const float*)d_in[5];
    const int*   dimidx = (const int*)d_in[7];

    float* param_out = (float*)d_out;
    float* lp_out    = param_out + (size_t)S_DIM * TDP;

    // lookback scratch in workspace: totals [S][32] f32, then flags [S] int
    float* tot   = (float*)d_ws;
    int*   flags = (int*)(tot + S_DIM * 32);
    hipMemsetAsync(flags, 0, S_DIM * sizeof(int), stream);  // capturable

    // 64 KB dynamic LDS: 8 waves x 8 k-steps x 64 lanes x 16 B;
    // grid = 2 time-halves x 256 samples; h = bid>>8 so all h=0 dispatch first
    fused_scan<<<S_DIM * 2, 512, 65536, stream>>>(noise, m, s_raw, a_raw, dimidx,
                                                  param_out, lp_out, tot, flags);
}

// Round 10
// 119.796 us; speedup vs baseline: 1.0554x; 1.0554x over previous
//
#include <hip/hip_runtime.h>

// ARMA posterior: per chain c in DP=32, sample s:
//   A[t]     = sigmoid(a_raw[t-1, dim_idx[d]])   (A[0]=0; same for all p in d)
//   sv[t]    = softplus(s_raw[t, dim_idx[d], p])
//   z        = (1-A)*m[t,di,p] + sv*noise
//   param[t] = z + A*param[t-1]
//   lp[t]    = -log(sv) - 0.5*log2pi - 0.5*noise^2
//
// R15 = R11 geometry (1024 thd, grid 256, DMA-to-LDS noise, pl-overwrite;
// best measured 113.7us) with the two __syncthreads REMOVED. Rationale:
// __syncthreads on gfx950 drains vmcnt(0) (compiler emits s_waitcnt
// vmcnt(0) before s_barrier), so R11 serialized three memory epochs:
// [DMA drain][lp-store drain @bar1][param stores after bar2]. The cross-
// wave scan only needs LDS ordering -> per-wave flag protocol: each wave
// publishes its totals + release-flag after phase A; every wave acquire-
// spins on waves 0..wg-1 only and folds <=15 carries redundantly (all 64
// lanes, keeping exec converged for the ci shuffles). Wave 0 never waits.
// lp + param stores now form one continuous un-drained stream. The single
// remaining barrier (flag zero-init) is issued before any vm op -> free.
#define T_DIM 1024
#define D_DIM 4
#define P_DIM 8
#define S_DIM 256
#define DP 32
#define TDP (T_DIM * DP)      // 32768 per sample
#define LOG2PI_F 1.8378770664093453f

typedef float vf4 __attribute__((ext_vector_type(4)));

__device__ __forceinline__ float sigmoid_fast(float x) {
    return __builtin_amdgcn_rcpf(1.0f + __expf(-x));
}

__global__ __launch_bounds__(1024) void fused_scan(
    const float* __restrict__ noise,
    const float* __restrict__ m,
    const float* __restrict__ s_raw,
    const float* __restrict__ a_raw,
    const int* __restrict__ dim_idx,
    float* __restrict__ param_out,
    float* __restrict__ lp_out)
{
    const int tid  = threadIdx.x;
    const int qc   = tid & 7;          // chain quad 0..7 (4 chains each)
    const int cj   = tid >> 3;         // time chunk 0..127 (8 steps each)
    const int cjw  = cj & 7;           // chunk within wave
    const int wg   = tid >> 6;         // wave 0..15
    const int lane = tid & 63;

    const int d  = qc >> 1;            // output dim 0..3
    const int p0 = (qc & 1) * 4;       // first of 4 consecutive p
    const int di = dim_idx[d];

    // dynamic LDS: per-wave noise tile, [wave][k][lane] * 4 floats = 128 KB
    extern __shared__ __align__(16) float nls[];
    __shared__ float wtp[16][32];      // wave-total p (per chain)
    __shared__ float wtm8[16][8];      // wave-total M (scalar per quad)
    __shared__ int   flags[16];        // per-wave publish flags

    const size_t sbase = (size_t)blockIdx.x * TDP;
    const int    off0  = cj * 8 * DP + qc * 4;

    float* lbase = nls + wg * 2048;    // this wave's 8KB region

    // ---- init: zero flags; the only barrier, before any vm op (free drain)
    if (tid < 16) flags[tid] = 0;
    __syncthreads();

    // ---- Phase 0a: DMA the wave's entire noise tile (8 x 1KB in flight).
    // Dest = wave-uniform base + lane*16; global src per-lane (R11-proven).
#pragma unroll
    for (int k = 0; k < 8; ++k) {
        const float* g = noise + sbase + off0 + (size_t)k * DP;
        __builtin_amdgcn_global_load_lds(
            (const __attribute__((address_space(1))) void*)g,
            (__attribute__((address_space(3))) void*)(lbase + k * 256),
            16, 0, 0);
    }
    asm volatile("s_waitcnt vmcnt(0)" ::: "memory");

    // ---- Phase 0b: local 8-step scan over 4 chains out of LDS.
    float Mk[8];
    vf4   rp = (vf4){0.f, 0.f, 0.f, 0.f};
    float rm = 1.0f;
#pragma unroll
    for (int k = 0; k < 8; ++k) {
        const int t = cj * 8 + k;
        const int o = off0 + k * DP;
        const vf4 n  = *(const vf4*)(lbase + k * 256 + lane * 4);
        const vf4 mv = *(const vf4*)(m     + (t * D_DIM + di) * P_DIM + p0);
        const vf4 sr = *(const vf4*)(s_raw + (t * D_DIM + di) * P_DIM + p0);

        float A = 0.0f;
        if (t > 0) A = sigmoid_fast(a_raw[(t - 1) * D_DIM + di]);
        const float oma = 1.0f - A;

        // softplus + negative-log-sv per chain
        vf4 sv, nl;
        sv.x = __logf(1.0f + __expf(sr.x));  nl.x = -__logf(sv.x) - 0.5f * LOG2PI_F;
        sv.y = __logf(1.0f + __expf(sr.y));  nl.y = -__logf(sv.y) - 0.5f * LOG2PI_F;
        sv.z = __logf(1.0f + __expf(sr.z));  nl.z = -__logf(sv.z) - 0.5f * LOG2PI_F;
        sv.w = __logf(1.0f + __expf(sr.w));  nl.w = -__logf(sv.w) - 0.5f * LOG2PI_F;

        vf4 lp;
        lp.x = nl.x - 0.5f * n.x * n.x;
        lp.y = nl.y - 0.5f * n.y * n.y;
        lp.z = nl.z - 0.5f * n.z * n.z;
        lp.w = nl.w - 0.5f * n.w * n.w;
        *(vf4*)(lp_out + sbase + o) = lp;   // fire-and-forget, never drained

        vf4 z;
        z.x = oma * mv.x + sv.x * n.x;
        z.y = oma * mv.y + sv.y * n.y;
        z.z = oma * mv.z + sv.z * n.z;
        z.w = oma * mv.w + sv.w * n.w;

        rp.x = z.x + A * rp.x;
        rp.y = z.y + A * rp.y;
        rp.z = z.z + A * rp.z;
        rp.w = z.w + A * rp.w;
        rm  *= A;
        Mk[k] = rm;
        // local prefix overwrites the consumed noise slot (keeps VGPR low)
        *(vf4*)(lbase + k * 256 + lane * 4) = rp;
    }

    // ---- Phase A: inclusive shfl-scan over 8 chunks within each wave
    //      combine(older(p1,m1), newer(p2,m2)) = (p2 + m2*p1, m1*m2)
#pragma unroll
    for (int off = 1; off < 8; off <<= 1) {
        const int dd = off * 8;        // lanes per chunk step
        vf4 pp;
        pp.x = __shfl_up(rp.x, dd, 64);
        pp.y = __shfl_up(rp.y, dd, 64);
        pp.z = __shfl_up(rp.z, dd, 64);
        pp.w = __shfl_up(rp.w, dd, 64);
        const float pm = __shfl_up(rm, dd, 64);
        if (cjw >= off) {
            rp.x += rm * pp.x;
            rp.y += rm * pp.y;
            rp.z += rm * pp.z;
            rp.w += rm * pp.w;
            rm *= pm;
        }
    }

    // ---- Phase B (barrier-free): publish wave totals + release flag.
    // Lanes 56..63 (cjw==7) hold the wave's inclusive totals for all 32
    // chains (4 each). Release-store by lane 63 orders the prior ds_writes
    // of the whole wave (program order within one instruction stream).
    if (cjw == 7 && wg < 15) {
        *(vf4*)&wtp[wg][qc * 4] = rp;
        wtm8[wg][qc] = rm;
    }
    if (lane == 63 && wg < 15)
        __hip_atomic_store(&flags[wg], 1, __ATOMIC_RELEASE,
                           __HIP_MEMORY_SCOPE_WORKGROUP);

    // ---- fold carry-in from waves 0..wg-1 (all 64 lanes redundantly, so
    // exec stays converged for the shuffles below). Wave 0 skips entirely.
    const int ch = lane & 31;
    float c = 0.0f;
    for (int gg = 0; gg < wg; ++gg) {
        while (__hip_atomic_load(&flags[gg], __ATOMIC_ACQUIRE,
                                 __HIP_MEMORY_SCOPE_WORKGROUP) == 0)
            __builtin_amdgcn_s_sleep(1);
        c = wtp[gg][ch] + wtm8[gg][ch >> 2] * c;
    }

    // ci for this thread's 4 chains, pulled from lanes 0..31 via shfl
    vf4 ci;
    ci.x = __shfl(c, qc * 4 + 0, 64);
    ci.y = __shfl(c, qc * 4 + 1, 64);
    ci.z = __shfl(c, qc * 4 + 2, 64);
    ci.w = __shfl(c, qc * 4 + 3, 64);

    // ---- Phase C: per-thread carry-in = excl-in-wave composed on wave carry
    vf4 ep;
    ep.x = __shfl_up(rp.x, 8, 64);
    ep.y = __shfl_up(rp.y, 8, 64);
    ep.z = __shfl_up(rp.z, 8, 64);
    ep.w = __shfl_up(rp.w, 8, 64);
    float em = __shfl_up(rm, 8, 64);
    if (cjw == 0) {
        ep = (vf4){0.f, 0.f, 0.f, 0.f};
        em = 1.0f;
    }
    vf4 carry;
    carry.x = ep.x + em * ci.x;
    carry.y = ep.y + em * ci.y;
    carry.z = ep.z + em * ci.z;
    carry.w = ep.w + em * ci.w;

    // ---- finalize: param[t] = pl[k] + Mk[k]*carry, pl read back from LDS
#pragma unroll
    for (int k = 0; k < 8; ++k) {
        const int o = off0 + k * DP;
        const vf4 pl = *(const vf4*)(lbase + k * 256 + lane * 4);
        vf4 pv;
        pv.x = pl.x + Mk[k] * carry.x;
        pv.y = pl.y + Mk[k] * carry.y;
        pv.z = pl.z + Mk[k] * carry.z;
        pv.w = pl.w + Mk[k] * carry.w;
        *(vf4*)(param_out + sbase + o) = pv;
    }
}

// ---------------------------------------------------------------------------
extern "C" void kernel_launch(void* const* d_in, const int* in_sizes, int n_in,
                              void* d_out, int out_size, void* d_ws, size_t ws_size,
                              hipStream_t stream)
{
    // 0:y 1:age 2:m(T,D,P) 3:s_raw(T,D,P) 4:a_raw(T-1,D,1) 5:noise(S,T,D,P)
    // 6:cond_sample 7:dim_idx(D) 8:compute_log_prob
    const float* m      = (const float*)d_in[2];
    const float* s_raw  = (const float*)d_in[3];
    const float* a_raw  = (const float*)d_in[4];
    const float* noise  = (const float*)d_in[5];
    const int*   dimidx = (const int*)d_in[7];

    float* param_out = (float*)d_out;
    float* lp_out    = param_out + (size_t)S_DIM * TDP;

    // 128 KB dynamic LDS: 16 waves x 8 k-steps x 64 lanes x 16 B
    fused_scan<<<S_DIM, 1024, 131072, stream>>>(noise, m, s_raw, a_raw, dimidx,
                                                param_out, lp_out);
}

// Round 11
// 119.231 us; speedup vs baseline: 1.0604x; 1.0047x over previous
//
#include <hip/hip_runtime.h>

// ARMA posterior: per chain c in DP=32, sample s:
//   A[t]     = sigmoid(a_raw[t-1, dim_idx[d]])   (A[0]=0; same for all p in d)
//   sv[t]    = softplus(s_raw[t, dim_idx[d], p])
//   z        = (1-A)*m[t,di,p] + sv*noise
//   param[t] = z + A*param[t-1]
//   lp[t]    = -log(sv) - 0.5*log2pi - 0.5*noise^2
//
// R16 = exact R11 revert (best harness-verified: 113.7us bench, ~25us kernel).
// Keep: global_load_lds DMA staging of noise (un-sinkable, 128KB/CU in
// flight -- the single biggest win, 131.8 -> 113.7), vf4/qc full-128B-line
// layout, pl-overwrite of consumed LDS slots, one upfront vmcnt(0).
// Rejected by measurement: chain-split 2 blocks/CU (R12, partial-line
// stores), per-step vmcnt(7) (R13, drains newer ops), time-split lookback
// (R14, sync cost), barrier-free flag scan (R15, spin >= barrier cost --
// the syncthreads vmcnt drains overlap across 16 waves and are ~free).
// Remaining ~8us over the 16us BW floor is phase-intrinsic; bench floor is
// ~88us of harness poison-fills.
#define T_DIM 1024
#define D_DIM 4
#define P_DIM 8
#define S_DIM 256
#define DP 32
#define TDP (T_DIM * DP)      // 32768 per sample
#define LOG2PI_F 1.8378770664093453f

typedef float vf4 __attribute__((ext_vector_type(4)));

__device__ __forceinline__ float sigmoid_fast(float x) {
    return __builtin_amdgcn_rcpf(1.0f + __expf(-x));
}

__global__ __launch_bounds__(1024) void fused_scan(
    const float* __restrict__ noise,
    const float* __restrict__ m,
    const float* __restrict__ s_raw,
    const float* __restrict__ a_raw,
    const int* __restrict__ dim_idx,
    float* __restrict__ param_out,
    float* __restrict__ lp_out)
{
    const int tid  = threadIdx.x;
    const int qc   = tid & 7;          // chain quad 0..7 (4 chains each)
    const int cj   = tid >> 3;         // time chunk 0..127 (8 steps each)
    const int cjw  = cj & 7;           // chunk within wave
    const int wg   = tid >> 6;         // wave 0..15
    const int lane = tid & 63;

    const int d  = qc >> 1;            // output dim 0..3
    const int p0 = (qc & 1) * 4;       // first of 4 consecutive p
    const int di = dim_idx[d];

    // dynamic LDS: per-wave noise tile, [wave][k][lane] * 4 floats = 128 KB
    extern __shared__ __align__(16) float nls[];
    __shared__ float wtp[16][32];      // wave-total p (per chain)
    __shared__ float wtm8[16][8];      // wave-total M (scalar per quad)
    __shared__ float wci[16][32];      // exclusive carry-in per wave

    const size_t sbase = (size_t)blockIdx.x * TDP;
    const int    off0  = cj * 8 * DP + qc * 4;

    float* lbase = nls + wg * 2048;    // this wave's 8KB region

    // ---- Phase 0a: DMA the wave's entire noise tile (8 x 1KB in flight).
    // Dest = wave-uniform base + lane*16; global src per-lane. Lane L
    // (= cjw*8+qc) reads 16B at off0+k*DP which is exactly slot lane*16.
#pragma unroll
    for (int k = 0; k < 8; ++k) {
        const float* g = noise + sbase + off0 + (size_t)k * DP;
        __builtin_amdgcn_global_load_lds(
            (const __attribute__((address_space(1))) void*)g,
            (__attribute__((address_space(3))) void*)(lbase + k * 256),
            16, 0, 0);
    }
    asm volatile("s_waitcnt vmcnt(0)" ::: "memory");

    // ---- Phase 0b: local 8-step scan over 4 chains out of LDS.
    float Mk[8];
    vf4   rp = (vf4){0.f, 0.f, 0.f, 0.f};
    float rm = 1.0f;
#pragma unroll
    for (int k = 0; k < 8; ++k) {
        const int t = cj * 8 + k;
        const int o = off0 + k * DP;
        const vf4 n  = *(const vf4*)(lbase + k * 256 + lane * 4);
        const vf4 mv = *(const vf4*)(m     + (t * D_DIM + di) * P_DIM + p0);
        const vf4 sr = *(const vf4*)(s_raw + (t * D_DIM + di) * P_DIM + p0);

        float A = 0.0f;
        if (t > 0) A = sigmoid_fast(a_raw[(t - 1) * D_DIM + di]);
        const float oma = 1.0f - A;

        // softplus + negative-log-sv per chain
        vf4 sv, nl;
        sv.x = __logf(1.0f + __expf(sr.x));  nl.x = -__logf(sv.x) - 0.5f * LOG2PI_F;
        sv.y = __logf(1.0f + __expf(sr.y));  nl.y = -__logf(sv.y) - 0.5f * LOG2PI_F;
        sv.z = __logf(1.0f + __expf(sr.z));  nl.z = -__logf(sv.z) - 0.5f * LOG2PI_F;
        sv.w = __logf(1.0f + __expf(sr.w));  nl.w = -__logf(sv.w) - 0.5f * LOG2PI_F;

        vf4 lp;
        lp.x = nl.x - 0.5f * n.x * n.x;
        lp.y = nl.y - 0.5f * n.y * n.y;
        lp.z = nl.z - 0.5f * n.z * n.z;
        lp.w = nl.w - 0.5f * n.w * n.w;
        *(vf4*)(lp_out + sbase + o) = lp;   // fire-and-forget

        vf4 z;
        z.x = oma * mv.x + sv.x * n.x;
        z.y = oma * mv.y + sv.y * n.y;
        z.z = oma * mv.z + sv.z * n.z;
        z.w = oma * mv.w + sv.w * n.w;

        rp.x = z.x + A * rp.x;
        rp.y = z.y + A * rp.y;
        rp.z = z.z + A * rp.z;
        rp.w = z.w + A * rp.w;
        rm  *= A;
        Mk[k] = rm;
        // local prefix overwrites the consumed noise slot (keeps VGPR low)
        *(vf4*)(lbase + k * 256 + lane * 4) = rp;
    }

    // ---- Phase A: inclusive shfl-scan over 8 chunks within each wave
    //      combine(older(p1,m1), newer(p2,m2)) = (p2 + m2*p1, m1*m2)
#pragma unroll
    for (int off = 1; off < 8; off <<= 1) {
        const int dd = off * 8;        // lanes per chunk step
        vf4 pp;
        pp.x = __shfl_up(rp.x, dd, 64);
        pp.y = __shfl_up(rp.y, dd, 64);
        pp.z = __shfl_up(rp.z, dd, 64);
        pp.w = __shfl_up(rp.w, dd, 64);
        const float pm = __shfl_up(rm, dd, 64);
        if (cjw >= off) {
            rp.x += rm * pp.x;
            rp.y += rm * pp.y;
            rp.z += rm * pp.z;
            rp.w += rm * pp.w;
            rm *= pm;
        }
    }

    // ---- Phase B: wave totals -> serial scan over 16 waves (32 lanes)
    if (cjw == 7) {
        *(vf4*)&wtp[wg][qc * 4] = rp;
        wtm8[wg][qc] = rm;
    }
    __syncthreads();
    if (tid < 32) {
        float c = 0.0f;
#pragma unroll
        for (int g = 0; g < 16; ++g) {
            wci[g][tid] = c;
            c = wtp[g][tid] + wtm8[g][tid >> 2] * c;
        }
    }
    __syncthreads();

    // ---- Phase C: per-thread carry-in = excl-in-wave composed on wave carry
    vf4 ep;
    ep.x = __shfl_up(rp.x, 8, 64);
    ep.y = __shfl_up(rp.y, 8, 64);
    ep.z = __shfl_up(rp.z, 8, 64);
    ep.w = __shfl_up(rp.w, 8, 64);
    float em = __shfl_up(rm, 8, 64);
    if (cjw == 0) {
        ep = (vf4){0.f, 0.f, 0.f, 0.f};
        em = 1.0f;
    }
    const vf4 ci = *(const vf4*)&wci[wg][qc * 4];
    vf4 carry;
    carry.x = ep.x + em * ci.x;
    carry.y = ep.y + em * ci.y;
    carry.z = ep.z + em * ci.z;
    carry.w = ep.w + em * ci.w;

    // ---- finalize: param[t] = pl[k] + Mk[k]*carry, pl read back from LDS
#pragma unroll
    for (int k = 0; k < 8; ++k) {
        const int o = off0 + k * DP;
        const vf4 pl = *(const vf4*)(lbase + k * 256 + lane * 4);
        vf4 pv;
        pv.x = pl.x + Mk[k] * carry.x;
        pv.y = pl.y + Mk[k] * carry.y;
        pv.z = pl.z + Mk[k] * carry.z;
        pv.w = pl.w + Mk[k] * carry.w;
        *(vf4*)(param_out + sbase + o) = pv;
    }
}

// ---------------------------------------------------------------------------
extern "C" void kernel_launch(void* const* d_in, const int* in_sizes, int n_in,
                              void* d_out, int out_size, void* d_ws, size_t ws_size,
                              hipStream_t stream)
{
    // 0:y 1:age 2:m(T,D,P) 3:s_raw(T,D,P) 4:a_raw(T-1,D,1) 5:noise(S,T,D,P)
    // 6:cond_sample 7:dim_idx(D) 8:compute_log_prob
    const float* m      = (const float*)d_in[2];
    const float* s_raw  = (const float*)d_in[3];
    const float* a_raw  = (const float*)d_in[4];
    const float* noise  = (const float*)d_in[5];
    const int*   dimidx = (const int*)d_in[7];

    float* param_out = (float*)d_out;
    float* lp_out    = param_out + (size_t)S_DIM * TDP;

    // 128 KB dynamic LDS: 16 waves x 8 k-steps x 64 lanes x 16 B
    fused_scan<<<S_DIM, 1024, 131072, stream>>>(noise, m, s_raw, a_raw, dimidx,
                                                param_out, lp_out);
}